// Round 9
// baseline (166.628 us; speedup 1.0000x reference)
//
#include <hip/hip_runtime.h>
#include <math.h>

#define BQ 8
#define MQ 64
#define REGMAX 16
#define KTOP 10
#define CH 4
#define EPSQ 1e-7f
#define SSEG 4
#define TRIG 256
#define CBUF (TRIG + SSEG * 256 + 16)  // max fill 1280 < 1296

__device__ __forceinline__ float frcp(float x) { return __builtin_amdgcn_rcpf(x); }

// state (floats): acc[32] = per-batch {sum(1-t), npos, bce_sum, pad} | cnt[8]@32
#define ST_CNT 32
#define ST_BYTES 256

// ---------------- decode: 1 anchor/thread, 64-deep load burst, no barriers until compaction ----------------
__global__ __launch_bounds__(256) void decode_kernel(
    const float* __restrict__ boxes, const float* __restrict__ scores,
    float4* __restrict__ pbc, float2* __restrict__ atc,
    unsigned int* __restrict__ iou_bits, float* __restrict__ state,
    int N, int bpb) {
  const int tid = threadIdx.x;
  const int b = blockIdx.x / bpb;
  const int n = (blockIdx.x - b * bpb) * 256 + tid;
  float* acc = state;
  int* cnt = (int*)(state + ST_CNT);

  __shared__ float4 s_sv[256];
  __shared__ float s_at[256];
  __shared__ int s_ix[256];
  __shared__ int s_cnt, s_base;
  if (tid == 0) s_cnt = 0;
  __syncthreads();

  float bce0 = 0.f;
  if (n < N) {
    const size_t i = (size_t)b * N + n;
    iou_bits[i] = 0u;
    float sc = scores[i];
    bce0 = fmaxf(sc, 0.f) + log1pf(__expf(-fabsf(sc)));

    // ---- 64 independent coalesced loads, all outstanding together ----
    const float* base = boxes + (size_t)b * 64 * (size_t)N + n;
    float x[64];
#pragma unroll
    for (int r = 0; r < 64; ++r) x[r] = base[(size_t)r * N];

    float ev[4];
#pragma unroll
    for (int k = 0; k < 4; ++k) {
      float mx = x[k * REGMAX];
#pragma unroll
      for (int r = 1; r < REGMAX; ++r) mx = fmaxf(mx, x[k * REGMAX + r]);
      float s = 0.f, ws = 0.f;
#pragma unroll
      for (int r = 0; r < REGMAX; ++r) {
        float e = __expf(x[k * REGMAX + r] - mx);
        s += e;
        ws += (float)r * e;
      }
      ev[k] = ws * frcp(s);
    }
    float w1 = ev[2] - ev[0], h1 = ev[3] - ev[1];
    if (w1 > 0.f && h1 > 0.f) {  // else ciou<=0 vs every target: reference masks topv>0
      int slot = atomicAdd(&s_cnt, 1);
      s_sv[slot] = make_float4(ev[0], ev[1], ev[2], ev[3]);
      s_at[slot] = atanf(w1 * frcp(h1 + EPSQ));
      s_ix[slot] = n;
    }
  }
  // wave-reduce bce, one atomic per wave
#pragma unroll
  for (int d = 1; d < 64; d <<= 1) bce0 += __shfl_xor(bce0, d, 64);
  if ((tid & 63) == 0) atomicAdd(&acc[b * 4 + 2], bce0);

  __syncthreads();
  const int bc = s_cnt;
  if (tid == 0) s_base = atomicAdd(&cnt[b], bc);
  __syncthreads();
  const int basei = s_base;
  for (int sl = tid; sl < bc; sl += 256) {
    pbc[(size_t)b * N + basei + sl] = s_sv[sl];
    atc[(size_t)b * N + basei + sl] = make_float2(s_at[sl], __int_as_float(s_ix[sl]));
  }
}

// ---------------- exact top-10 of LDS buffer (wave 0 only) ----------------
__device__ __forceinline__ void select_top10(
    float* s_bv, int* s_bi, float* s_winv, int* s_wini,
    int* s_cnt, float* s_sthr, int c, int tid) {
  if (tid < 64) {
    for (int r = 0; r < KTOP; ++r) {
      float bv = 0.f;
      int bs = 0xffff;
      for (int sl = tid; sl < c; sl += 64) {
        float v = s_bv[sl];
        if (v > bv) { bv = v; bs = sl; }
      }
      unsigned long long key =
          ((unsigned long long)__float_as_uint(bv) << 32) | (unsigned int)bs;
#pragma unroll
      for (int d = 1; d < 64; d <<= 1) {
        unsigned long long o = __shfl_xor(key, d, 64);
        if (o > key) key = o;
      }
      if (tid == 0) {
        float wv = __uint_as_float((unsigned int)(key >> 32));
        int ws = (int)(key & 0xffffu);
        s_winv[r] = wv;
        if (wv > 0.f && ws != 0xffff) {
          s_wini[r] = s_bi[ws];
          s_bv[ws] = 0.f;
        } else {
          s_wini[r] = 0;
        }
      }
    }
    if (tid < KTOP) { s_bv[tid] = s_winv[tid]; s_bi[tid] = s_wini[tid]; }
    if (tid == 0) { *s_cnt = KTOP; *s_sthr = s_winv[KTOP - 1]; }
  }
}

// ---------------- topk1: (b,m,chunk) blocks over compacted list; threshold + buffer ----------------
__global__ __launch_bounds__(256) void topk1_kernel(
    const float4* __restrict__ pbc, const float2* __restrict__ atc,
    const float* __restrict__ targets, float* __restrict__ cand_v,
    int* __restrict__ cand_i, const float* __restrict__ state, int N) {
  const int blk = blockIdx.x;
  const int chunk = blk & (CH - 1);
  const int bm = blk >> 2;
  const int b = bm >> 6;
  const int m = bm & 63;
  const int tid = threadIdx.x;
  const int* cnt = (const int*)(state + ST_CNT);

  __shared__ float s_bv[CBUF];
  __shared__ int s_bi[CBUF];
  __shared__ float s_winv[KTOP];
  __shared__ int s_wini[KTOP];
  __shared__ int s_cnt;
  __shared__ float s_sthr;
  if (tid == 0) { s_cnt = 0; s_sthr = 0.f; }
  __syncthreads();

  const float4 t = ((const float4*)targets)[b * MQ + m];
  const float x21 = t.x, y21 = t.y, x22 = t.z, y22 = t.w;
  const float w2 = x22 - x21, h2 = y22 - y21;
  const float atan_t = atanf(w2 * frcp(h2 + EPSQ));
  const float area2 = w2 * h2;
  const float sumx2 = x21 + x22, sumy2 = y21 + y22;
  const float CPI = 4.0f / (float)(M_PI * M_PI);

  const int cntb = cnt[b];
  const int cch = (cntb + CH - 1) / CH;
  const int j0 = chunk * cch;
  const int j1 = min(cntb, j0 + cch);
  float sthr = 0.f;
  const float4* pbb = pbc + (size_t)b * N;
  const float2* pab = atc + (size_t)b * N;

  for (int basei = j0; basei < j1; basei += SSEG * 256) {
#pragma unroll
    for (int s = 0; s < SSEG; ++s) {
      int j = basei + s * 256 + tid;
      if (j < j1) {
        float4 p = pbb[j];
        float2 ai = pab[j];
        float x11 = p.x, y11 = p.y, x12 = p.z, y12 = p.w;
        float w1 = x12 - x11, h1 = y12 - y11;
        float iw = fmaxf(fminf(x12, x22) - fmaxf(x11, x21), 0.f);
        float ih = fmaxf(fminf(y12, y22) - fmaxf(y11, y21), 0.f);
        float inter = iw * ih;
        float uni = w1 * h1 + area2 - inter + EPSQ;
        float iou = inter * frcp(uni);
        float cw = fmaxf(x12, x22) - fminf(x11, x21);
        float ch = fmaxf(y12, y22) - fminf(y11, y21);
        float c2 = cw * cw + ch * ch + EPSQ;
        float dx = sumx2 - x11 - x12;
        float dy = sumy2 - y11 - y12;
        float rho2 = (dx * dx + dy * dy) * 0.25f;
        float da = atan_t - ai.x;
        float v = CPI * da * da;
        float alpha = v * frcp(v - iou + 1.f + EPSQ);
        float ciou = iou - rho2 * frcp(c2) - alpha * v;
        if (ciou > sthr) {
          int slot = atomicAdd(&s_cnt, 1);
          s_bv[slot] = ciou;
          s_bi[slot] = __float_as_int(ai.y);
        }
      }
    }
    __syncthreads();
    int c = s_cnt;
    __syncthreads();
    if (c > TRIG) {
      select_top10(s_bv, s_bi, s_winv, s_wini, &s_cnt, &s_sthr, c, tid);
      __syncthreads();
    }
    sthr = s_sthr;
  }

  int c = s_cnt;
  if (c > KTOP) {
    select_top10(s_bv, s_bi, s_winv, s_wini, &s_cnt, &s_sthr, c, tid);
    __syncthreads();
    c = KTOP;
  }
  if (tid < KTOP) {
    cand_v[(bm * CH + chunk) * KTOP + tid] = (tid < c) ? s_bv[tid] : 0.f;
    cand_i[(bm * CH + chunk) * KTOP + tid] = (tid < c) ? s_bi[tid] : 0;
  }
}

// ---------------- topk2: merge 40->10 per (b,m); atomicMax + exact delta accounting ----------------
__global__ __launch_bounds__(64) void topk2_kernel(
    const float* __restrict__ cand_v, const int* __restrict__ cand_i,
    const float* __restrict__ scores, unsigned int* __restrict__ iou_bits,
    float* __restrict__ state, int N) {
  const int bm = blockIdx.x;
  const int b = bm >> 6;
  const int tid = threadIdx.x;
  float* acc = state;
  const int NC = CH * KTOP;  // 40
  __shared__ float mv[NC];
  __shared__ int mi[NC];
  if (tid < NC) {
    mv[tid] = cand_v[bm * NC + tid];
    mi[tid] = cand_i[bm * NC + tid];
  }
  __syncthreads();
  if (tid < NC) {
    float v = mv[tid];
    if (v > 0.f) {
      int rank = 0;
#pragma unroll
      for (int i2 = 0; i2 < NC; ++i2)
        rank += (mv[i2] > v) || (mv[i2] == v && i2 < tid);
      if (rank < KTOP) {
        int ix = mi[tid];
        unsigned int vb = __float_as_uint(v);
        unsigned int old = atomicMax(&iou_bits[(size_t)b * N + ix], vb);
        if (old < vb) {  // raised this anchor's max: account exact delta (telescopes)
          float vold = __uint_as_float(old);  // 0.f when old==0
          bool was = (old != 0u);
          atomicAdd(&acc[b * 4 + 0], was ? (vold - v) : (1.f - v));
          if (!was) atomicAdd(&acc[b * 4 + 1], 1.f);
          atomicAdd(&acc[b * 4 + 2], -scores[(size_t)b * N + ix] * (v - vold));
        }
      }
    }
  }
}

// ---------------- finalize ----------------
__global__ void finalize_kernel(const float* __restrict__ acc,
                                float* __restrict__ out, int N) {
  if (threadIdx.x == 0 && blockIdx.x == 0) {
    float box = 0.f, obj = 0.f;
    for (int bb = 0; bb < BQ; ++bb) {
      float sb = acc[bb * 4 + 0];
      float np = acc[bb * 4 + 1];
      float sc = acc[bb * 4 + 2];
      box += (np > 0.f) ? sb / fmaxf(np, 1.f) : 0.f;
      obj += sc / (float)N;
    }
    out[0] = (7.5f * box + obj) / (float)BQ;
    out[1] = box;
    out[2] = obj;
  }
}

extern "C" void kernel_launch(void* const* d_in, const int* in_sizes, int n_in,
                              void* d_out, int out_size, void* d_ws, size_t ws_size,
                              hipStream_t stream) {
  const float* boxes = (const float*)d_in[0];
  const float* scores = (const float*)d_in[1];
  const float* targets = (const float*)d_in[2];
  float* out = (float*)d_out;
  const int N = in_sizes[1] / BQ;  // scores is [B, N]

  char* ws = (char*)d_ws;
  size_t pbc_bytes = (size_t)BQ * N * sizeof(float4);
  size_t atc_bytes = (size_t)BQ * N * sizeof(float2);
  size_t iou_bytes = (size_t)BQ * N * sizeof(unsigned int);
  size_t cand_bytes = (size_t)BQ * MQ * CH * KTOP * sizeof(float);

  float4* pbc = (float4*)ws;                   ws += pbc_bytes;
  float2* atc = (float2*)ws;                   ws += atc_bytes;
  unsigned int* iou_bits = (unsigned int*)ws;  ws += iou_bytes;
  float* cand_v = (float*)ws;                  ws += cand_bytes;
  int* cand_i = (int*)ws;                      ws += cand_bytes;
  float* state = (float*)ws;

  hipMemsetAsync(state, 0, ST_BYTES, stream);

  const int bpb = (N + 255) / 256;
  decode_kernel<<<BQ * bpb, 256, 0, stream>>>(boxes, scores, pbc, atc,
                                              iou_bits, state, N, bpb);
  topk1_kernel<<<BQ * MQ * CH, 256, 0, stream>>>(pbc, atc, targets, cand_v,
                                                 cand_i, state, N);
  topk2_kernel<<<BQ * MQ, 64, 0, stream>>>(cand_v, cand_i, scores, iou_bits,
                                           state, N);
  finalize_kernel<<<1, 64, 0, stream>>>(state, out, N);
}

// Round 10
// 139.307 us; speedup vs baseline: 1.1961x; 1.1961x over previous
//
#include <hip/hip_runtime.h>
#include <math.h>

#define BQ 8
#define MQ 64
#define REGMAX 16
#define KTOP 10
#define EPSQ 1e-7f
#define MBUF 1344  // >= bpb*KTOP = 1330 for N=34000

__device__ __forceinline__ float frcp(float x) { return __builtin_amdgcn_rcpf(x); }

// state (floats): acc[32] = per-batch {sum(1-t), npos, bce_sum, pad}
#define ST_BYTES 256

// DFL expected value for one side: 16 NAMED scalar loads (guaranteed registers,
// guaranteed 16-deep load burst -> MLP; an x[16] array risks demotion/serialization).
__device__ __forceinline__ float dfl_side(const float* __restrict__ p, size_t Ns) {
  float x0 = p[0];
  float x1 = p[Ns];
  float x2 = p[2 * Ns];
  float x3 = p[3 * Ns];
  float x4 = p[4 * Ns];
  float x5 = p[5 * Ns];
  float x6 = p[6 * Ns];
  float x7 = p[7 * Ns];
  float x8 = p[8 * Ns];
  float x9 = p[9 * Ns];
  float x10 = p[10 * Ns];
  float x11 = p[11 * Ns];
  float x12 = p[12 * Ns];
  float x13 = p[13 * Ns];
  float x14 = p[14 * Ns];
  float x15 = p[15 * Ns];
  float mx = fmaxf(fmaxf(fmaxf(fmaxf(x0, x1), fmaxf(x2, x3)),
                         fmaxf(fmaxf(x4, x5), fmaxf(x6, x7))),
                   fmaxf(fmaxf(fmaxf(x8, x9), fmaxf(x10, x11)),
                         fmaxf(fmaxf(x12, x13), fmaxf(x14, x15))));
  float s = 0.f, ws = 0.f, e;
  e = __expf(x0 - mx); s += e;
  e = __expf(x1 - mx); s += e; ws += 1.f * e;
  e = __expf(x2 - mx); s += e; ws += 2.f * e;
  e = __expf(x3 - mx); s += e; ws += 3.f * e;
  e = __expf(x4 - mx); s += e; ws += 4.f * e;
  e = __expf(x5 - mx); s += e; ws += 5.f * e;
  e = __expf(x6 - mx); s += e; ws += 6.f * e;
  e = __expf(x7 - mx); s += e; ws += 7.f * e;
  e = __expf(x8 - mx); s += e; ws += 8.f * e;
  e = __expf(x9 - mx); s += e; ws += 9.f * e;
  e = __expf(x10 - mx); s += e; ws += 10.f * e;
  e = __expf(x11 - mx); s += e; ws += 11.f * e;
  e = __expf(x12 - mx); s += e; ws += 12.f * e;
  e = __expf(x13 - mx); s += e; ws += 13.f * e;
  e = __expf(x14 - mx); s += e; ws += 14.f * e;
  e = __expf(x15 - mx); s += e; ws += 15.f * e;
  return ws * frcp(s);
}

// ---------------- kernel 1: decode (register bursts) + screen + per-block per-target top-10 ----------------
__global__ __launch_bounds__(256) void decode_topk_kernel(
    const float* __restrict__ boxes, const float* __restrict__ scores,
    const float* __restrict__ targets, unsigned int* __restrict__ iou_bits,
    uint2* __restrict__ cand, float* __restrict__ acc, int N, int bpb) {
  const int tid = threadIdx.x;
  const int b = blockIdx.x / bpb;
  const int blk = blockIdx.x - b * bpb;
  const int a0 = blk * 256;
  const int w = tid >> 6;
  const int l = tid & 63;

  __shared__ float4 s_sv[256];
  __shared__ float s_at[256];
  __shared__ int s_ix[256];
  __shared__ float s_hv[4 * MQ * KTOP];
  __shared__ int s_hi[4 * MQ * KTOP];
  __shared__ uint2 s_mg[MQ * KTOP];
  __shared__ int s_cnt;
  __shared__ float s_bce;
  if (tid == 0) { s_cnt = 0; s_bce = 0.f; }
  __syncthreads();

  // ---- phase 1: decode 4 sides, each a 16-deep named-register load burst ----
  const int n = a0 + tid;
  float bce0 = 0.f;
  if (n < N) {
    const size_t i = (size_t)b * N + n;
    iou_bits[i] = 0u;
    float sc = scores[i];
    bce0 = fmaxf(sc, 0.f) + log1pf(__expf(-fabsf(sc)));
    const size_t Ns = (size_t)N;
    const float* base = boxes + (size_t)(b * 64) * Ns + n;
    float ev0 = dfl_side(base, Ns);
    float ev1 = dfl_side(base + 16 * Ns, Ns);
    float ev2 = dfl_side(base + 32 * Ns, Ns);
    float ev3 = dfl_side(base + 48 * Ns, Ns);
    float w1 = ev2 - ev0, h1 = ev3 - ev1;
    if (w1 > 0.f && h1 > 0.f) {  // else ciou<=0 vs every target: reference masks topv>0
      int slot = atomicAdd(&s_cnt, 1);
      s_sv[slot] = make_float4(ev0, ev1, ev2, ev3);
      s_at[slot] = atanf(w1 * frcp(h1 + EPSQ));
      s_ix[slot] = n;
    }
  }
#pragma unroll
  for (int d = 1; d < 64; d <<= 1) bce0 += __shfl_xor(bce0, d, 64);
  if (l == 0) atomicAdd(&s_bce, bce0);
  __syncthreads();
  const int nsurv = s_cnt;
  if (tid == 0) atomicAdd(&acc[b * 4 + 2], s_bce);

  // ---- phase 2: lane = target; wave w scans its survivor quarter (LDS broadcast) ----
  const float4 t = ((const float4*)targets)[b * MQ + l];
  const float x21 = t.x, y21 = t.y, x22 = t.z, y22 = t.w;
  const float w2 = x22 - x21, h2 = y22 - y21;
  const float atan_t = atanf(w2 * frcp(h2 + EPSQ));
  const float area2 = w2 * h2, sumx2 = x21 + x22, sumy2 = y21 + y22;
  const float CPI = 4.0f / (float)(M_PI * M_PI);

  float hv0 = 0.f, hv1 = 0.f, hv2 = 0.f, hv3 = 0.f, hv4 = 0.f;
  float hv5 = 0.f, hv6 = 0.f, hv7 = 0.f, hv8 = 0.f, hv9 = 0.f;
  int hi0 = 0, hi1 = 0, hi2 = 0, hi3 = 0, hi4 = 0;
  int hi5 = 0, hi6 = 0, hi7 = 0, hi8 = 0, hi9 = 0;

  const int qlen = (nsurv + 3) >> 2;
  const int j0 = w * qlen;
  const int j1 = min(nsurv, j0 + qlen);
  for (int j = j0; j < j1; ++j) {
    float4 p = s_sv[j];  // same addr across lanes -> LDS broadcast
    float pa = s_at[j];
    int ixj = s_ix[j];
    float x11 = p.x, y11 = p.y, x12 = p.z, y12 = p.w;
    float w1 = x12 - x11, h1 = y12 - y11;
    float iw = fmaxf(fminf(x12, x22) - fmaxf(x11, x21), 0.f);
    float ih = fmaxf(fminf(y12, y22) - fmaxf(y11, y21), 0.f);
    float inter = iw * ih;
    float uni = w1 * h1 + area2 - inter + EPSQ;
    float iou = inter * frcp(uni);
    float cw = fmaxf(x12, x22) - fminf(x11, x21);
    float ch = fmaxf(y12, y22) - fminf(y11, y21);
    float c2 = cw * cw + ch * ch + EPSQ;
    float dx = sumx2 - x11 - x12;
    float dy = sumy2 - y11 - y12;
    float rho2 = (dx * dx + dy * dy) * 0.25f;
    float da = atan_t - pa;
    float v = CPI * da * da;
    float alpha = v * frcp(v - iou + 1.f + EPSQ);
    float ciou = iou - rho2 * frcp(c2) - alpha * v;
    if (ciou > hv9) {
      float cv = ciou;
      int ci = ixj;
#define INS(vk, ik)                         \
  {                                         \
    bool gt = cv > vk;                      \
    float tv_ = vk; int ti_ = ik;           \
    vk = gt ? cv : vk; ik = gt ? ci : ik;   \
    cv = gt ? tv_ : cv; ci = gt ? ti_ : ci; \
  }
      INS(hv0, hi0) INS(hv1, hi1) INS(hv2, hi2) INS(hv3, hi3) INS(hv4, hi4)
      INS(hv5, hi5) INS(hv6, hi6) INS(hv7, hi7) INS(hv8, hi8) INS(hv9, hi9)
#undef INS
    }
  }
  const int hb = (w * MQ + l) * KTOP;
  s_hv[hb + 0] = hv0; s_hi[hb + 0] = hi0;
  s_hv[hb + 1] = hv1; s_hi[hb + 1] = hi1;
  s_hv[hb + 2] = hv2; s_hi[hb + 2] = hi2;
  s_hv[hb + 3] = hv3; s_hi[hb + 3] = hi3;
  s_hv[hb + 4] = hv4; s_hi[hb + 4] = hi4;
  s_hv[hb + 5] = hv5; s_hi[hb + 5] = hi5;
  s_hv[hb + 6] = hv6; s_hi[hb + 6] = hi6;
  s_hv[hb + 7] = hv7; s_hi[hb + 7] = hi7;
  s_hv[hb + 8] = hv8; s_hi[hb + 8] = hi8;
  s_hv[hb + 9] = hv9; s_hi[hb + 9] = hi9;
  __syncthreads();

  // ---- phase 3: wave 0, lane m: 4-way merge -> s_mg; coalesced copy-out ----
  if (w == 0) {
    const int m = l;
    int p0 = 0, p1 = 0, p2 = 0, p3 = 0;
    for (int r = 0; r < KTOP; ++r) {
      float c0 = s_hv[(0 * MQ + m) * KTOP + p0];
      float c1 = s_hv[(1 * MQ + m) * KTOP + p1];
      float c2m = s_hv[(2 * MQ + m) * KTOP + p2];
      float c3 = s_hv[(3 * MQ + m) * KTOP + p3];
      float best = c0; int bw = 0;
      if (c1 > best) { best = c1; bw = 1; }
      if (c2m > best) { best = c2m; bw = 2; }
      if (c3 > best) { best = c3; bw = 3; }
      int psel = (bw == 0) ? p0 : (bw == 1) ? p1 : (bw == 2) ? p2 : p3;
      int bidx = s_hi[(bw * MQ + m) * KTOP + psel];
      s_mg[m * KTOP + r] = make_uint2(__float_as_uint(best), (unsigned)bidx);
      if (bw == 0) p0 = min(p0 + 1, KTOP - 1);
      else if (bw == 1) p1 = min(p1 + 1, KTOP - 1);
      else if (bw == 2) p2 = min(p2 + 1, KTOP - 1);
      else p3 = min(p3 + 1, KTOP - 1);
    }
  }
  __syncthreads();
  uint2* obase = cand + (size_t)(b * bpb + blk) * (MQ * KTOP);
  for (int sl = tid; sl < MQ * KTOP; sl += 256) obase[sl] = s_mg[sl];
}

// ---------------- exact top-10 of LDS buffer (wave 0 only) ----------------
__device__ __forceinline__ void select_top10(
    float* s_bv, int* s_bi, float* s_winv, int* s_wini,
    int* s_cnt, int c, int tid) {
  if (tid < 64) {
    for (int r = 0; r < KTOP; ++r) {
      float bv = 0.f;
      int bs = 0xffff;
      for (int sl = tid; sl < c; sl += 64) {
        float v = s_bv[sl];
        if (v > bv) { bv = v; bs = sl; }
      }
      unsigned long long key =
          ((unsigned long long)__float_as_uint(bv) << 32) | (unsigned int)bs;
#pragma unroll
      for (int d = 1; d < 64; d <<= 1) {
        unsigned long long o = __shfl_xor(key, d, 64);
        if (o > key) key = o;
      }
      if (tid == 0) {
        float wv = __uint_as_float((unsigned int)(key >> 32));
        int ws = (int)(key & 0xffffu);
        s_winv[r] = wv;
        if (wv > 0.f && ws != 0xffff) {
          s_wini[r] = s_bi[ws];
          s_bv[ws] = 0.f;
        } else {
          s_wini[r] = 0;
        }
      }
    }
    if (tid < KTOP) { s_bv[tid] = s_winv[tid]; s_bi[tid] = s_wini[tid]; }
    if (tid == 0) *s_cnt = KTOP;
  }
}

// ---------------- kernel 2: merge 133x10 per (b,m) -> top-10; scatter + exact delta ----------------
__global__ __launch_bounds__(256) void merge_kernel(
    const uint2* __restrict__ cand, const float* __restrict__ scores,
    unsigned int* __restrict__ iou_bits, float* __restrict__ acc,
    int N, int bpb) {
  const int bm = blockIdx.x;
  const int b = bm >> 6;
  const int m = bm & 63;
  const int tid = threadIdx.x;
  const int NC = bpb * KTOP;  // 1330 for N=34000

  __shared__ float s_bv[MBUF];
  __shared__ int s_bi[MBUF];
  __shared__ float s_winv[KTOP];
  __shared__ int s_wini[KTOP];
  __shared__ int s_cnt;
  if (tid == 0) s_cnt = 0;
  __syncthreads();

  for (int k2 = tid; k2 < NC; k2 += 256) {
    int blkk = k2 / KTOP;
    int r = k2 - blkk * KTOP;
    uint2 e = cand[((size_t)(b * bpb + blkk) * MQ + m) * KTOP + r];
    float v = __uint_as_float(e.x);
    if (v > 0.f) {
      int slot = atomicAdd(&s_cnt, 1);  // slot < NC <= MBUF
      s_bv[slot] = v;
      s_bi[slot] = (int)e.y;
    }
  }
  __syncthreads();
  int c = s_cnt;
  __syncthreads();
  if (c > KTOP) {
    select_top10(s_bv, s_bi, s_winv, s_wini, &s_cnt, c, tid);
    __syncthreads();
    c = KTOP;
  }
  if (tid < KTOP && tid < c) {
    float v = s_bv[tid];
    if (v > 0.f) {
      int ix = s_bi[tid];
      unsigned int vb = __float_as_uint(v);
      unsigned int old = atomicMax(&iou_bits[(size_t)b * N + ix], vb);
      if (old < vb) {  // raised this anchor's max: account exact delta (telescopes)
        float vold = __uint_as_float(old);  // 0.f when old==0
        bool was = (old != 0u);
        atomicAdd(&acc[b * 4 + 0], was ? (vold - v) : (1.f - v));
        if (!was) atomicAdd(&acc[b * 4 + 1], 1.f);
        atomicAdd(&acc[b * 4 + 2], -scores[(size_t)b * N + ix] * (v - vold));
      }
    }
  }
}

// ---------------- finalize ----------------
__global__ void finalize_kernel(const float* __restrict__ acc,
                                float* __restrict__ out, int N) {
  if (threadIdx.x == 0 && blockIdx.x == 0) {
    float box = 0.f, obj = 0.f;
    for (int bb = 0; bb < BQ; ++bb) {
      float sb = acc[bb * 4 + 0];
      float np = acc[bb * 4 + 1];
      float sc = acc[bb * 4 + 2];
      box += (np > 0.f) ? sb / fmaxf(np, 1.f) : 0.f;
      obj += sc / (float)N;
    }
    out[0] = (7.5f * box + obj) / (float)BQ;
    out[1] = box;
    out[2] = obj;
  }
}

extern "C" void kernel_launch(void* const* d_in, const int* in_sizes, int n_in,
                              void* d_out, int out_size, void* d_ws, size_t ws_size,
                              hipStream_t stream) {
  const float* boxes = (const float*)d_in[0];
  const float* scores = (const float*)d_in[1];
  const float* targets = (const float*)d_in[2];
  float* out = (float*)d_out;
  const int N = in_sizes[1] / BQ;  // scores is [B, N]

  const int bpb = (N + 255) / 256;  // 133

  char* ws = (char*)d_ws;
  size_t cand_bytes = (size_t)BQ * bpb * MQ * KTOP * sizeof(uint2);
  size_t iou_bytes = (size_t)BQ * N * sizeof(unsigned int);

  uint2* cand = (uint2*)ws;                    ws += cand_bytes;
  unsigned int* iou_bits = (unsigned int*)ws;  ws += iou_bytes;
  float* state = (float*)ws;                   // ST_BYTES

  hipMemsetAsync(state, 0, ST_BYTES, stream);

  decode_topk_kernel<<<BQ * bpb, 256, 0, stream>>>(boxes, scores, targets,
                                                   iou_bits, cand, state, N, bpb);
  merge_kernel<<<BQ * MQ, 256, 0, stream>>>(cand, scores, iou_bits, state, N, bpb);
  finalize_kernel<<<1, 64, 0, stream>>>(state, out, N);
}